// Round 9
// baseline (33.931 us; speedup 1.0000x reference)
//
#include <hip/hip_runtime.h>
#include <hip/hip_bf16.h>

// CRPS loss — R8: DIAGNOSTIC round on the champion R2 structure.
// Graph = [main][main][reduce]; the duplicated main node writes identical
// partials (idempotent, deterministic), so correctness is unchanged and
//   main_dur + node_gap = dur_us(R8) - dur_us(R2=19.3)
// which splits "main kernel time" from "graph/launch overhead" using the
// bench's own timer (rocprof top-5 is saturated by 40 us harness fills).
//
// crps(p) = (1/N) sum_i |x_i - y| - (1/N^2) sum_{i<j} |x_i - x_j|
// N = 20, P = 524288. Traffic 44 MB cold (harness fills flush L3) -> main
// floor ~7 us at 6.3 TB/s.

constexpr int N_ENS = 20;

typedef float f4 __attribute__((ext_vector_type(4)));

__global__ __launch_bounds__(256) void crps_partial_v4(
    const f4* __restrict__ fc,    // (N_ENS, nv) in float4 units
    const f4* __restrict__ obs,   // (nv)
    const float* __restrict__ fc_s,   // scalar view for tail
    const float* __restrict__ obs_s,
    float* __restrict__ partial,  // (gridDim.x)
    int nv, int P)
{
    const int stride = gridDim.x * blockDim.x;
    const int gtid = blockIdx.x * blockDim.x + threadIdx.x;
    float local = 0.0f;

    for (int v = gtid; v < nv; v += stride) {
        f4 x[N_ENS];
        #pragma unroll
        for (int i = 0; i < N_ENS; ++i)
            x[i] = fc[(size_t)i * (size_t)nv + (size_t)v];
        const f4 y = obs[v];

        #pragma unroll
        for (int c = 0; c < 4; ++c) {
            float xc[N_ENS];
            #pragma unroll
            for (int i = 0; i < N_ENS; ++i) xc[i] = x[i][c];
            const float yc = y[c];

            float t1 = 0.0f;
            #pragma unroll
            for (int i = 0; i < N_ENS; ++i) t1 += fabsf(xc[i] - yc);

            float t2 = 0.0f;
            #pragma unroll
            for (int i = 0; i < N_ENS; ++i) {
                #pragma unroll
                for (int j = i + 1; j < N_ENS; ++j)
                    t2 += fabsf(xc[i] - xc[j]);
            }
            local += t1 * (1.0f / N_ENS) - t2 * (1.0f / (N_ENS * N_ENS));
        }
    }

    // scalar tail (P % 4 != 0) — no-op for P=524288
    for (int p = 4 * nv + gtid; p < P; p += stride) {
        float xc[N_ENS];
        #pragma unroll
        for (int i = 0; i < N_ENS; ++i) xc[i] = fc_s[(size_t)i * (size_t)P + p];
        const float yc = obs_s[p];
        float t1 = 0.0f, t2 = 0.0f;
        #pragma unroll
        for (int i = 0; i < N_ENS; ++i) t1 += fabsf(xc[i] - yc);
        #pragma unroll
        for (int i = 0; i < N_ENS; ++i) {
            #pragma unroll
            for (int j = i + 1; j < N_ENS; ++j)
                t2 += fabsf(xc[i] - xc[j]);
        }
        local += t1 * (1.0f / N_ENS) - t2 * (1.0f / (N_ENS * N_ENS));
    }

    // wave (64-lane) reduction
    #pragma unroll
    for (int off = 32; off > 0; off >>= 1)
        local += __shfl_down(local, off, 64);

    __shared__ float wsum[4];  // 256 threads = 4 waves
    const int lane = threadIdx.x & 63;
    const int wid  = threadIdx.x >> 6;
    if (lane == 0) wsum[wid] = local;
    __syncthreads();
    if (threadIdx.x == 0)
        partial[blockIdx.x] = wsum[0] + wsum[1] + wsum[2] + wsum[3];
}

__global__ __launch_bounds__(64) void crps_reduce_w(
    const float* __restrict__ partial,
    int nblocks,
    float* __restrict__ out,
    float inv_total)
{
    double s = 0.0;
    for (int i = threadIdx.x; i < nblocks; i += 64)
        s += (double)partial[i];

    #pragma unroll
    for (int off = 32; off > 0; off >>= 1)
        s += __shfl_down(s, off, 64);

    if (threadIdx.x == 0)
        out[0] = (float)(s * (double)inv_total);
}

extern "C" void kernel_launch(void* const* d_in, const int* in_sizes, int n_in,
                              void* d_out, int out_size, void* d_ws, size_t ws_size,
                              hipStream_t stream) {
    const float* fc  = (const float*)d_in[0];
    const float* obs = (const float*)d_in[1];
    float* out = (float*)d_out;

    const int P  = in_sizes[1];   // B*C*D*H*W = 524288
    const int nv = P >> 2;        // float4 count per ensemble row = 131072

    const int block = 256;
    int nblocks = (nv + block - 1) / block;   // 512
    if (nblocks < 1) nblocks = 1;
    if (nblocks > 4096) nblocks = 4096;

    float* partial = (float*)d_ws;            // nblocks floats

    // DIAGNOSTIC: main node duplicated (idempotent) to measure its per-node
    // cost via dur_us delta against the single-main R2 baseline (19.3 us).
    crps_partial_v4<<<nblocks, block, 0, stream>>>(
        (const f4*)fc, (const f4*)obs, fc, obs, partial, nv, P);
    crps_partial_v4<<<nblocks, block, 0, stream>>>(
        (const f4*)fc, (const f4*)obs, fc, obs, partial, nv, P);
    crps_reduce_w<<<1, 64, 0, stream>>>(partial, nblocks, out, 1.0f / (float)P);
}

// Round 10
// 21.623 us; speedup vs baseline: 1.5692x; 1.5692x over previous
//
#include <hip/hip_runtime.h>
#include <hip/hip_bf16.h>

// CRPS loss:
//   crps(p) = (1/N) sum_i |x_i - y| - (1/N^2) sum_{i<j} |x_i - x_j|
//   out = mean_p crps(p)
// N = 20, P = 524288. Two-kernel structure (kernel boundary = the only cheap
// cross-XCD fence; R4/5/6 evidence). Main kernel measured ~14.6 us (R8
// duplicate-node diagnostic) vs 2.8 us VALU floor / 7 us HBM floor ->
// stall-bound, prime suspect: serial FP add chains (no fast-math => compiler
// cannot reassociate the 190-term pairwise sum).
// R9 change: multi-accumulator trees (4x for t2, 2x for t1) to cut dependent
// chain length ~5x. All accumulator indices are compile-time after unroll.

constexpr int N_ENS = 20;

typedef float f4 __attribute__((ext_vector_type(4)));

__global__ __launch_bounds__(256) void crps_partial_v4(
    const f4* __restrict__ fc,    // (N_ENS, nv) in float4 units
    const f4* __restrict__ obs,   // (nv)
    const float* __restrict__ fc_s,   // scalar view for tail
    const float* __restrict__ obs_s,
    float* __restrict__ partial,  // (gridDim.x)
    int nv, int P)
{
    const int stride = gridDim.x * blockDim.x;
    const int gtid = blockIdx.x * blockDim.x + threadIdx.x;
    float local = 0.0f;

    for (int v = gtid; v < nv; v += stride) {
        f4 x[N_ENS];
        #pragma unroll
        for (int i = 0; i < N_ENS; ++i)
            x[i] = fc[(size_t)i * (size_t)nv + (size_t)v];
        const f4 y = obs[v];

        #pragma unroll
        for (int c = 0; c < 4; ++c) {
            float xc[N_ENS];
            #pragma unroll
            for (int i = 0; i < N_ENS; ++i) xc[i] = x[i][c];
            const float yc = y[c];

            // t1: |x_i - y| with 2 accumulators (chain 20 -> 10)
            float b0 = 0.0f, b1 = 0.0f;
            #pragma unroll
            for (int i = 0; i < N_ENS; ++i) {
                if ((i & 1) == 0) b0 += fabsf(xc[i] - yc);
                else              b1 += fabsf(xc[i] - yc);
            }

            // t2: pairwise with 4 round-robin accumulators (chain 190 -> ~48)
            float a[4] = {0.0f, 0.0f, 0.0f, 0.0f};
            #pragma unroll
            for (int i = 0; i < N_ENS; ++i) {
                #pragma unroll
                for (int j = i + 1; j < N_ENS; ++j) {
                    a[(i + j) & 3] += fabsf(xc[i] - xc[j]);  // const idx after unroll
                }
            }

            local += (b0 + b1) * (1.0f / N_ENS)
                   - ((a[0] + a[1]) + (a[2] + a[3])) * (1.0f / (N_ENS * N_ENS));
        }
    }

    // scalar tail (P % 4 != 0) — no-op for P=524288
    for (int p = 4 * nv + gtid; p < P; p += stride) {
        float xc[N_ENS];
        #pragma unroll
        for (int i = 0; i < N_ENS; ++i) xc[i] = fc_s[(size_t)i * (size_t)P + p];
        const float yc = obs_s[p];
        float b0 = 0.0f, b1 = 0.0f;
        #pragma unroll
        for (int i = 0; i < N_ENS; ++i) {
            if ((i & 1) == 0) b0 += fabsf(xc[i] - yc);
            else              b1 += fabsf(xc[i] - yc);
        }
        float a[4] = {0.0f, 0.0f, 0.0f, 0.0f};
        #pragma unroll
        for (int i = 0; i < N_ENS; ++i) {
            #pragma unroll
            for (int j = i + 1; j < N_ENS; ++j)
                a[(i + j) & 3] += fabsf(xc[i] - xc[j]);
        }
        local += (b0 + b1) * (1.0f / N_ENS)
               - ((a[0] + a[1]) + (a[2] + a[3])) * (1.0f / (N_ENS * N_ENS));
    }

    // wave (64-lane) reduction
    #pragma unroll
    for (int off = 32; off > 0; off >>= 1)
        local += __shfl_down(local, off, 64);

    __shared__ float wsum[4];  // 256 threads = 4 waves
    const int lane = threadIdx.x & 63;
    const int wid  = threadIdx.x >> 6;
    if (lane == 0) wsum[wid] = local;
    __syncthreads();
    if (threadIdx.x == 0)
        partial[blockIdx.x] = wsum[0] + wsum[1] + wsum[2] + wsum[3];
}

__global__ __launch_bounds__(64) void crps_reduce_w(
    const float* __restrict__ partial,
    int nblocks,
    float* __restrict__ out,
    float inv_total)
{
    double s = 0.0;
    for (int i = threadIdx.x; i < nblocks; i += 64)
        s += (double)partial[i];

    #pragma unroll
    for (int off = 32; off > 0; off >>= 1)
        s += __shfl_down(s, off, 64);

    if (threadIdx.x == 0)
        out[0] = (float)(s * (double)inv_total);
}

extern "C" void kernel_launch(void* const* d_in, const int* in_sizes, int n_in,
                              void* d_out, int out_size, void* d_ws, size_t ws_size,
                              hipStream_t stream) {
    const float* fc  = (const float*)d_in[0];
    const float* obs = (const float*)d_in[1];
    float* out = (float*)d_out;

    const int P  = in_sizes[1];   // B*C*D*H*W = 524288
    const int nv = P >> 2;        // float4 count per ensemble row = 131072

    const int block = 256;
    int nblocks = (nv + block - 1) / block;   // 512
    if (nblocks < 1) nblocks = 1;
    if (nblocks > 4096) nblocks = 4096;

    float* partial = (float*)d_ws;            // nblocks floats

    crps_partial_v4<<<nblocks, block, 0, stream>>>(
        (const f4*)fc, (const f4*)obs, fc, obs, partial, nv, P);
    crps_reduce_w<<<1, 64, 0, stream>>>(partial, nblocks, out, 1.0f / (float)P);
}